// Round 10
// baseline (343.179 us; speedup 1.0000x reference)
//
#include <hip/hip_runtime.h>
#include <hip/hip_fp16.h>

// GCNEncoder: two GCNConv(+relu) layers + global mean pool.
// N=50000 nodes, E=1.6M edges, 128 ch, 64 graphs.
// R10: 2-pass 64-ch aggregation (xw chunk-major [2][N][64]; per-pass gather
// working set 6.4MB ~ per-XCD L2; full 128B-line gathers, 32-lane groups,
// 8 in flight). scan2 fused into scan1 (last-block trick). epk/OUT nontemporal.

#define CH 128
#define BSH 7         // 128 nodes per bucket
#define NBLK 1024     // level-1 edge-chunk blocks
#define MAXNB 512     // LDS histogram capacity (NB = ceil(N/128) = 391)
#define PCH 32        // pool chunks per graph
#define LDW 136       // Wt LDS stride

typedef __attribute__((ext_vector_type(8))) short bf16x8;
typedef __attribute__((ext_vector_type(4))) float f32x4;
typedef __attribute__((ext_vector_type(2))) float f32x2;

static __device__ __forceinline__ unsigned short f2bf(float f) {
    unsigned u = __float_as_uint(f);
    unsigned r = (u + 0x7FFF + ((u >> 16) & 1)) >> 16;  // RNE
    return (unsigned short)r;
}
static __device__ __forceinline__ float bflo(unsigned v) { return __uint_as_float(v << 16); }
static __device__ __forceinline__ float bfhi(unsigned v) { return __uint_as_float(v & 0xFFFF0000u); }
static __device__ __forceinline__ float f16u(unsigned bits15) {
    __half_raw hr; hr.x = (unsigned short)(bits15 & 0x7FFF);
    return __half2float(*reinterpret_cast<__half*>(&hr));
}
static __device__ __forceinline__ unsigned u16f(float f) {  // f >= 0
    __half hh = __float2half(f);
    return (unsigned)(*reinterpret_cast<unsigned short*>(&hh)) & 0x7FFF;
}

// ---- level-1 count: per-(bucket, chunk-block) histogram, LDS atomics only
__global__ __launch_bounds__(256) void k_sort1a(const int* __restrict__ col,
                                                int* __restrict__ H, int* __restrict__ cnt,
                                                int E, int NB, int chunk) {
    __shared__ int hist[MAXNB];
    int t = threadIdx.x, blk = blockIdx.x;
    if (blk == 0 && t == 0) *cnt = 0;  // reset scan1's last-block counter
    for (int i = t; i < NB; i += 256) hist[i] = 0;
    __syncthreads();
    int s = blk * chunk, e1 = min(s + chunk, E);
    for (int e = s + t; e < e1; e += 256) atomicAdd(&hist[col[e] >> BSH], 1);
    __syncthreads();
    for (int i = t; i < NB; i += 256) H[(size_t)i * NBLK + blk] = hist[i];
}

// ---- scan: block-local exclusive in place + last block scans bsum (fused phase 2)
__global__ __launch_bounds__(1024) void k_scan1(int* __restrict__ data,
                                                int* __restrict__ bsum,
                                                int* __restrict__ cnt, int n, int nb) {
    __shared__ int sd[1024];
    __shared__ int lastFlag;
    int t = threadIdx.x;
    int i = blockIdx.x * 1024 + t;
    int v = (i < n) ? data[i] : 0;
    sd[t] = v;
    __syncthreads();
    for (int off = 1; off < 1024; off <<= 1) {
        int u = (t >= off) ? sd[t - off] : 0;
        __syncthreads();
        sd[t] += u;
        __syncthreads();
    }
    if (i < n) data[i] = sd[t] - v;
    if (t == 1023) {
        bsum[blockIdx.x] = sd[1023];
        __threadfence();
        lastFlag = (atomicAdd(cnt, 1) == (int)gridDim.x - 1);
    }
    __syncthreads();
    if (lastFlag) {
        __threadfence();
        int v2 = (t < nb) ? bsum[t] : 0;
        sd[t] = v2;
        __syncthreads();
        for (int off = 1; off < 1024; off <<= 1) {
            int u = (t >= off) ? sd[t - off] : 0;
            __syncthreads();
            sd[t] += u;
            __syncthreads();
        }
        if (t < nb) bsum[t] = sd[t] - v2;
    }
}

// ---- level-1 scatter into bucket order via LDS cursors (disjoint regions)
__global__ __launch_bounds__(256) void k_sort1b(const int* __restrict__ row,
                                                const int* __restrict__ col,
                                                const float* __restrict__ ew,
                                                const int* __restrict__ Hs,
                                                const int* __restrict__ bsum,
                                                int2* __restrict__ pairs2,
                                                int E, int NB, int chunk) {
    __shared__ int cur[MAXNB];
    int t = threadIdx.x, blk = blockIdx.x;
    for (int i = t; i < NB; i += 256) cur[i] = Hs[(size_t)i * NBLK + blk] + bsum[i];
    __syncthreads();
    int s = blk * chunk, e1 = min(s + chunk, E);
    for (int e = s + t; e < e1; e += 256) {
        int c = col[e];
        int pos = atomicAdd(&cur[c >> BSH], 1);
        pairs2[pos] = make_int2(row[e] | ((c & 127) << 17), __float_as_int(ew[e]));
    }
}

// ---- level-2: per-bucket node sort + rowptr + degree (dis), LDS only.
// Output: epk[pos] = { f16(w):15 | src:17 } (4B per edge).
__global__ __launch_bounds__(256) void k_sort2(const int* __restrict__ Hs,
                                               const int* __restrict__ bsum,
                                               const int2* __restrict__ pairs2,
                                               unsigned* __restrict__ epk,
                                               int* __restrict__ rowptr,
                                               float* __restrict__ dis,
                                               int E, int N, int NB) {
    __shared__ int hist[128];
    __shared__ int pref[128];
    __shared__ float wsum[128];
    int b = blockIdx.x, t = threadIdx.x;
    int n0 = b << BSH;
    int s = Hs[(size_t)b * NBLK] + bsum[b];
    int e1 = (b + 1 < NB) ? Hs[(size_t)(b + 1) * NBLK] + bsum[b + 1] : E;
    if (t < 128) { hist[t] = 0; wsum[t] = 0.f; }
    __syncthreads();
    for (int e = s + t; e < e1; e += 256)
        atomicAdd(&hist[(unsigned)pairs2[e].x >> 17], 1);
    __syncthreads();
    if (t < 128) pref[t] = hist[t];
    __syncthreads();
    for (int off = 1; off < 128; off <<= 1) {
        int v = 0;
        if (t < 128 && t >= off) v = pref[t - off];
        __syncthreads();
        if (t < 128) pref[t] += v;
        __syncthreads();
    }
    if (t < 128) {
        int excl = pref[t] - hist[t];
        int node = n0 + t;
        if (node < N) rowptr[node] = s + excl;
        hist[t] = s + excl;  // cursor
    }
    if (b == NB - 1 && t == 0) rowptr[N] = E;
    __syncthreads();
    for (int e = s + t; e < e1; e += 256) {
        int2 pr = pairs2[e];
        int li = (unsigned)pr.x >> 17;
        float w = __int_as_float(pr.y);
        int pos = atomicAdd(&hist[li], 1);
        epk[pos] = (unsigned)(pr.x & 0x1FFFF) | (u16f(w) << 17);
        atomicAdd(&wsum[li], w);
    }
    __syncthreads();
    if (t < 128 && n0 + t < N) dis[n0 + t] = rsqrtf(1.0f + wsum[t]);
}

// In-place: epk[e] {f16(w),src} -> {f16(dn*w*dis[src]), src}
__global__ __launch_bounds__(64) void k_norm(const int* __restrict__ rowptr,
                                             unsigned* __restrict__ epk,
                                             const float* __restrict__ dis, int N) {
    int n = blockIdx.x;
    int lane = threadIdx.x;
    float dn = dis[n];
    int e0 = rowptr[n], e1 = rowptr[n + 1];
    for (int e = e0 + lane; e < e1; e += 64) {
        unsigned v = epk[e];
        unsigned src = v & 0x1FFFF;
        float nn = dn * f16u(v >> 17) * dis[src];
        epk[e] = src | (u16f(nn) << 17);
    }
}

// Y (chunk-major [2][N][64] bf16) = X[N,128](f32) @ W[128,128](f32) via bf16 MFMA.
__global__ __launch_bounds__(512) void k_gemm(const float* __restrict__ X,
                                              const float* __restrict__ W,
                                              unsigned short* __restrict__ Y, int N) {
    __shared__ unsigned short Wt[128 * LDW];
    int tid = threadIdx.x;
    for (int i = tid; i < 4096; i += 512) {  // i indexes float4 of W[k][c]
        float4 v = ((const float4*)W)[i];
        int k = i >> 5;
        int c = (i & 31) * 4;
        Wt[(c + 0) * LDW + k] = f2bf(v.x);
        Wt[(c + 1) * LDW + k] = f2bf(v.y);
        Wt[(c + 2) * LDW + k] = f2bf(v.z);
        Wt[(c + 3) * LDW + k] = f2bf(v.w);
    }
    __syncthreads();
    int w = tid >> 6, lane = tid & 63;
    int l15 = lane & 15, kg = lane >> 4;
    int r = blockIdx.x * 128 + w * 16 + l15;
    f32x4 acc[8];
#pragma unroll
    for (int ct = 0; ct < 8; ++ct) acc[ct] = (f32x4){0.f, 0.f, 0.f, 0.f};
#pragma unroll
    for (int kb = 0; kb < 128; kb += 32) {
        union { unsigned u[4]; bf16x8 v; } a;
        if (r < N) {
            const float4* xp = (const float4*)(X + (size_t)r * CH + kb + kg * 8);
            float4 x0 = xp[0], x1 = xp[1];
            a.u[0] = ((unsigned)f2bf(x0.y) << 16) | f2bf(x0.x);
            a.u[1] = ((unsigned)f2bf(x0.w) << 16) | f2bf(x0.z);
            a.u[2] = ((unsigned)f2bf(x1.y) << 16) | f2bf(x1.x);
            a.u[3] = ((unsigned)f2bf(x1.w) << 16) | f2bf(x1.z);
        } else {
            a.u[0] = a.u[1] = a.u[2] = a.u[3] = 0;
        }
#pragma unroll
        for (int ct = 0; ct < 8; ++ct) {
            bf16x8 b = *(const bf16x8*)&Wt[(ct * 16 + l15) * LDW + kb + kg * 8];
            acc[ct] = __builtin_amdgcn_mfma_f32_16x16x32_bf16(a.v, b, acc[ct], 0, 0, 0);
        }
    }
    int orow = blockIdx.x * 128 + w * 16 + kg * 4;
#pragma unroll
    for (int ct = 0; ct < 8; ++ct) {
        int c = ct * 16 + l15;
        unsigned short* Yb = Y + (size_t)(c >> 6) * N * 64 + (c & 63);
#pragma unroll
        for (int j = 0; j < 4; ++j) {
            int rr = orow + j;
            if (rr < N) Yb[(size_t)rr * 64] = f2bf(acc[ct][j]);
        }
    }
}

// 64-ch-chunk aggregation. 4 nodes/block (4 waves); wave = 2 groups x 32 lanes.
// Each group: every 2nd edge, 8 gathers (full 128B lines) in flight.
__global__ __launch_bounds__(256) void k_aggc(const unsigned* __restrict__ XWC,
                                              const float* __restrict__ dis,
                                              const int* __restrict__ rowptr,
                                              const unsigned* __restrict__ epk,
                                              const float* __restrict__ bias,
                                              float* __restrict__ OUT,
                                              int col0, int N) {
    int n = blockIdx.x * 4 + (threadIdx.x >> 6);
    if (n >= N) return;
    int lane = threadIdx.x & 63;
    int g = lane >> 5, li = lane & 31;
    float ax = 0.f, ay = 0.f;
    int e0 = rowptr[n], e1 = rowptr[n + 1];
    int e = e0 + g;
    for (; e + 14 < e1; e += 16) {
        unsigned p0 = __builtin_nontemporal_load(&epk[e]);
        unsigned p1 = __builtin_nontemporal_load(&epk[e + 2]);
        unsigned p2 = __builtin_nontemporal_load(&epk[e + 4]);
        unsigned p3 = __builtin_nontemporal_load(&epk[e + 6]);
        unsigned p4 = __builtin_nontemporal_load(&epk[e + 8]);
        unsigned p5 = __builtin_nontemporal_load(&epk[e + 10]);
        unsigned p6 = __builtin_nontemporal_load(&epk[e + 12]);
        unsigned p7 = __builtin_nontemporal_load(&epk[e + 14]);
        unsigned v0 = XWC[(size_t)(p0 & 0x1FFFF) * 32 + li];
        unsigned v1 = XWC[(size_t)(p1 & 0x1FFFF) * 32 + li];
        unsigned v2 = XWC[(size_t)(p2 & 0x1FFFF) * 32 + li];
        unsigned v3 = XWC[(size_t)(p3 & 0x1FFFF) * 32 + li];
        unsigned v4 = XWC[(size_t)(p4 & 0x1FFFF) * 32 + li];
        unsigned v5 = XWC[(size_t)(p5 & 0x1FFFF) * 32 + li];
        unsigned v6 = XWC[(size_t)(p6 & 0x1FFFF) * 32 + li];
        unsigned v7 = XWC[(size_t)(p7 & 0x1FFFF) * 32 + li];
        float n0 = f16u(p0 >> 17), n1 = f16u(p1 >> 17);
        float n2 = f16u(p2 >> 17), n3 = f16u(p3 >> 17);
        float n4 = f16u(p4 >> 17), n5 = f16u(p5 >> 17);
        float n6 = f16u(p6 >> 17), n7 = f16u(p7 >> 17);
        ax += n0 * bflo(v0) + n1 * bflo(v1) + n2 * bflo(v2) + n3 * bflo(v3)
            + n4 * bflo(v4) + n5 * bflo(v5) + n6 * bflo(v6) + n7 * bflo(v7);
        ay += n0 * bfhi(v0) + n1 * bfhi(v1) + n2 * bfhi(v2) + n3 * bfhi(v3)
            + n4 * bfhi(v4) + n5 * bfhi(v5) + n6 * bfhi(v6) + n7 * bfhi(v7);
    }
    for (; e < e1; e += 2) {
        unsigned p = __builtin_nontemporal_load(&epk[e]);
        unsigned v = XWC[(size_t)(p & 0x1FFFF) * 32 + li];
        float nn = f16u(p >> 17);
        ax += nn * bflo(v);
        ay += nn * bfhi(v);
    }
    if (g == 0) {  // self-loop
        float dn = dis[n];
        float sn = dn * dn;
        unsigned a = XWC[(size_t)n * 32 + li];
        ax += sn * bflo(a);
        ay += sn * bfhi(a);
    }
    ax += __shfl_xor(ax, 32);
    ay += __shfl_xor(ay, 32);
    if (g == 0) {
        float2 b = *(const float2*)&bias[col0 + li * 2];
        f32x2 o;
        o.x = fmaxf(ax + b.x, 0.f);
        o.y = fmaxf(ay + b.y, 0.f);
        __builtin_nontemporal_store(o, (f32x2*)&OUT[(size_t)n * CH + col0 + li * 2]);
    }
}

__device__ __forceinline__ int lowerb(const int* a, int n, int v) {
    int lo = 0, hi = n;
    while (lo < hi) {
        int m = (lo + hi) >> 1;
        if (a[m] < v) lo = m + 1; else hi = m;
    }
    return lo;
}

// Stage 1: 64 graphs x PCH chunks, partial channel sums.
__global__ __launch_bounds__(128) void k_pool1(const float* __restrict__ H,
                                               const int* __restrict__ batch,
                                               float* __restrict__ partial, int N) {
    __shared__ int ss[2];
    int g = blockIdx.x / PCH;
    int k = blockIdx.x % PCH;
    if (threadIdx.x == 0) {
        ss[0] = lowerb(batch, N, g);
        ss[1] = lowerb(batch, N, g + 1);
    }
    __syncthreads();
    int s = ss[0], len = ss[1] - ss[0];
    int cs = s + (int)(((long long)len * k) / PCH);
    int ce = s + (int)(((long long)len * (k + 1)) / PCH);
    int ch = threadIdx.x;
    float a0 = 0.f, a1 = 0.f;
    int n = cs;
    for (; n + 2 <= ce; n += 2) {
        a0 += H[(size_t)(n + 0) * CH + ch];
        a1 += H[(size_t)(n + 1) * CH + ch];
    }
    for (; n < ce; ++n) a0 += H[(size_t)n * CH + ch];
    partial[(size_t)blockIdx.x * CH + ch] = a0 + a1;
}

// Stage 2: reduce PCH partials per graph, divide by count.
__global__ __launch_bounds__(128) void k_pool2(const float* __restrict__ partial,
                                               const int* __restrict__ batch,
                                               float* __restrict__ P, int N) {
    __shared__ int ss[2];
    int g = blockIdx.x;
    if (threadIdx.x == 0) {
        ss[0] = lowerb(batch, N, g);
        ss[1] = lowerb(batch, N, g + 1);
    }
    __syncthreads();
    int ch = threadIdx.x;
    float a = 0.f;
#pragma unroll
    for (int k = 0; k < PCH; ++k) a += partial[(size_t)(g * PCH + k) * CH + ch];
    float c = (float)(ss[1] - ss[0]);
    P[(size_t)g * CH + ch] = a / fmaxf(c, 1.f);
}

extern "C" void kernel_launch(void* const* d_in, const int* in_sizes, int n_in,
                              void* d_out, int out_size, void* d_ws, size_t ws_size,
                              hipStream_t stream) {
    const float* x     = (const float*)d_in[0];
    const int*   ei    = (const int*)d_in[1];
    const float* ew    = (const float*)d_in[2];
    const int*   batch = (const int*)d_in[3];
    const float* W1    = (const float*)d_in[4];
    const float* b1    = (const float*)d_in[5];
    const float* W2    = (const float*)d_in[6];
    const float* b2    = (const float*)d_in[7];

    int N = in_sizes[0] / CH;   // 50000
    int E = in_sizes[1] / 2;    // 1600000
    const int* row = ei;
    const int* col = ei + E;

    float* out    = (float*)d_out;
    float* h      = out;
    float* pooled = out + (size_t)N * CH;

    int NB    = (N + 127) >> BSH;          // 391
    int chunk = (E + NBLK - 1) / NBLK;     // 1563
    int n2    = NB * NBLK;                 // 400384

    // ws: dis | rowptr | H(n2+1; partial aliases) | bsum(1024)+cnt | epk(E*4) | xw(pairs2 aliases)
    char* wsb = (char*)d_ws;
    size_t oN  = ((size_t)N * 4 + 255) & ~(size_t)255;
    size_t oN1 = ((size_t)(N + 1) * 4 + 255) & ~(size_t)255;
    size_t oH  = ((size_t)(n2 + 1) * 4 + 255) & ~(size_t)255;
    size_t oB  = 8192;
    size_t oE1 = ((size_t)E * 4 + 255) & ~(size_t)255;
    float* dis    = (float*)wsb;
    int*   rowptr = (int*)(wsb + oN);
    int*   H      = (int*)(wsb + oN + oN1);
    int*   bsum   = (int*)(wsb + oN + oN1 + oH);
    int*   cnt    = bsum + 1024;
    unsigned* epk = (unsigned*)(wsb + oN + oN1 + oH + oB);
    unsigned short* xw = (unsigned short*)(wsb + oN + oN1 + oH + oB + oE1);
    int2*  pairs2 = (int2*)xw;     // E*8 = 12.8MB == N*CH*2; dead before k_gemm
    float* partial = (float*)H;    // H dead after sort2; 1MB <= 1.6MB

    int sb2 = (n2 + 1023) / 1024;  // 391

    // ---- CSR build: two-level LDS counting sort (no global atomics) ----
    k_sort1a<<<NBLK, 256, 0, stream>>>(col, H, cnt, E, NB, chunk);
    k_scan1<<<sb2, 1024, 0, stream>>>(H, bsum, cnt, n2, sb2);
    k_sort1b<<<NBLK, 256, 0, stream>>>(row, col, ew, H, bsum, pairs2, E, NB, chunk);
    k_sort2<<<NB, 256, 0, stream>>>(H, bsum, pairs2, epk, rowptr, dis, E, N, NB);
    k_norm<<<N, 64, 0, stream>>>(rowptr, epk, dis, N);

    int gb = (N + 127) / 128;
    int ab = (N + 3) / 4;
    const unsigned* xw32 = (const unsigned*)xw;
    // ---- layer 1 ----
    k_gemm<<<gb, 512, 0, stream>>>(x, W1, xw, N);
    k_aggc<<<ab, 256, 0, stream>>>(xw32, dis, rowptr, epk, b1, h, 0, N);
    k_aggc<<<ab, 256, 0, stream>>>(xw32 + (size_t)N * 32, dis, rowptr, epk, b1, h, 64, N);
    // ---- layer 2 ----
    k_gemm<<<gb, 512, 0, stream>>>(h, W2, xw, N);
    k_aggc<<<ab, 256, 0, stream>>>(xw32, dis, rowptr, epk, b2, h, 0, N);
    k_aggc<<<ab, 256, 0, stream>>>(xw32 + (size_t)N * 32, dis, rowptr, epk, b2, h, 64, N);
    // ---- mean pool (two-stage) ----
    k_pool1<<<64 * PCH, 128, 0, stream>>>(h, batch, partial, N);
    k_pool2<<<64, 128, 0, stream>>>(partial, batch, pooled, N);
}

// Round 11
// 233.712 us; speedup vs baseline: 1.4684x; 1.4684x over previous
//
#include <hip/hip_runtime.h>
#include <hip/hip_fp16.h>

// GCNEncoder: two GCNConv(+relu) layers + global mean pool.
// N=50000 nodes, E=1.6M edges, 128 ch, 64 graphs.
// R11: revert R10 (2-pass 64ch agg was latency-bound: traffic fell 30% but
// time doubled -> gather is REQUEST-bound, not fetch-bound). R9 k_agg +
// uint4 edge loads + 16 gathers in flight (MLP 8->16). Fused scan kept.

#define CH 128
#define BSH 7         // 128 nodes per bucket
#define NBLK 1024     // level-1 edge-chunk blocks
#define MAXNB 512     // LDS histogram capacity (NB = ceil(N/128) = 391)
#define PCH 32        // pool chunks per graph
#define LDW 136       // Wt LDS stride

typedef __attribute__((ext_vector_type(8))) short bf16x8;
typedef __attribute__((ext_vector_type(4))) float f32x4;

static __device__ __forceinline__ unsigned short f2bf(float f) {
    unsigned u = __float_as_uint(f);
    unsigned r = (u + 0x7FFF + ((u >> 16) & 1)) >> 16;  // RNE
    return (unsigned short)r;
}
static __device__ __forceinline__ float bflo(unsigned v) { return __uint_as_float(v << 16); }
static __device__ __forceinline__ float bfhi(unsigned v) { return __uint_as_float(v & 0xFFFF0000u); }
static __device__ __forceinline__ float f16u(unsigned bits15) {
    __half_raw hr; hr.x = (unsigned short)(bits15 & 0x7FFF);
    return __half2float(*reinterpret_cast<__half*>(&hr));
}
static __device__ __forceinline__ unsigned u16f(float f) {  // f >= 0
    __half hh = __float2half(f);
    return (unsigned)(*reinterpret_cast<unsigned short*>(&hh)) & 0x7FFF;
}

// ---- level-1 count: per-(bucket, chunk-block) histogram, LDS atomics only
__global__ __launch_bounds__(256) void k_sort1a(const int* __restrict__ col,
                                                int* __restrict__ H, int* __restrict__ cnt,
                                                int E, int NB, int chunk) {
    __shared__ int hist[MAXNB];
    int t = threadIdx.x, blk = blockIdx.x;
    if (blk == 0 && t == 0) *cnt = 0;  // reset scan1's last-block counter
    for (int i = t; i < NB; i += 256) hist[i] = 0;
    __syncthreads();
    int s = blk * chunk, e1 = min(s + chunk, E);
    for (int e = s + t; e < e1; e += 256) atomicAdd(&hist[col[e] >> BSH], 1);
    __syncthreads();
    for (int i = t; i < NB; i += 256) H[(size_t)i * NBLK + blk] = hist[i];
}

// ---- scan: block-local exclusive in place + last block scans bsum (fused phase 2)
__global__ __launch_bounds__(1024) void k_scan1(int* __restrict__ data,
                                                int* __restrict__ bsum,
                                                int* __restrict__ cnt, int n, int nb) {
    __shared__ int sd[1024];
    __shared__ int lastFlag;
    int t = threadIdx.x;
    int i = blockIdx.x * 1024 + t;
    int v = (i < n) ? data[i] : 0;
    sd[t] = v;
    __syncthreads();
    for (int off = 1; off < 1024; off <<= 1) {
        int u = (t >= off) ? sd[t - off] : 0;
        __syncthreads();
        sd[t] += u;
        __syncthreads();
    }
    if (i < n) data[i] = sd[t] - v;
    if (t == 1023) {
        bsum[blockIdx.x] = sd[1023];
        __threadfence();
        lastFlag = (atomicAdd(cnt, 1) == (int)gridDim.x - 1);
    }
    __syncthreads();
    if (lastFlag) {
        __threadfence();
        int v2 = (t < nb) ? bsum[t] : 0;
        sd[t] = v2;
        __syncthreads();
        for (int off = 1; off < 1024; off <<= 1) {
            int u = (t >= off) ? sd[t - off] : 0;
            __syncthreads();
            sd[t] += u;
            __syncthreads();
        }
        if (t < nb) bsum[t] = sd[t] - v2;
    }
}

// ---- level-1 scatter into bucket order via LDS cursors (disjoint regions)
__global__ __launch_bounds__(256) void k_sort1b(const int* __restrict__ row,
                                                const int* __restrict__ col,
                                                const float* __restrict__ ew,
                                                const int* __restrict__ Hs,
                                                const int* __restrict__ bsum,
                                                int2* __restrict__ pairs2,
                                                int E, int NB, int chunk) {
    __shared__ int cur[MAXNB];
    int t = threadIdx.x, blk = blockIdx.x;
    for (int i = t; i < NB; i += 256) cur[i] = Hs[(size_t)i * NBLK + blk] + bsum[i];
    __syncthreads();
    int s = blk * chunk, e1 = min(s + chunk, E);
    for (int e = s + t; e < e1; e += 256) {
        int c = col[e];
        int pos = atomicAdd(&cur[c >> BSH], 1);
        pairs2[pos] = make_int2(row[e] | ((c & 127) << 17), __float_as_int(ew[e]));
    }
}

// ---- level-2: per-bucket node sort + rowptr + degree (dis), LDS only.
// Output: epk[pos] = { f16(w):15 | src:17 } (4B per edge).
__global__ __launch_bounds__(256) void k_sort2(const int* __restrict__ Hs,
                                               const int* __restrict__ bsum,
                                               const int2* __restrict__ pairs2,
                                               unsigned* __restrict__ epk,
                                               int* __restrict__ rowptr,
                                               float* __restrict__ dis,
                                               int E, int N, int NB) {
    __shared__ int hist[128];
    __shared__ int pref[128];
    __shared__ float wsum[128];
    int b = blockIdx.x, t = threadIdx.x;
    int n0 = b << BSH;
    int s = Hs[(size_t)b * NBLK] + bsum[b];
    int e1 = (b + 1 < NB) ? Hs[(size_t)(b + 1) * NBLK] + bsum[b + 1] : E;
    if (t < 128) { hist[t] = 0; wsum[t] = 0.f; }
    __syncthreads();
    for (int e = s + t; e < e1; e += 256)
        atomicAdd(&hist[(unsigned)pairs2[e].x >> 17], 1);
    __syncthreads();
    if (t < 128) pref[t] = hist[t];
    __syncthreads();
    for (int off = 1; off < 128; off <<= 1) {
        int v = 0;
        if (t < 128 && t >= off) v = pref[t - off];
        __syncthreads();
        if (t < 128) pref[t] += v;
        __syncthreads();
    }
    if (t < 128) {
        int excl = pref[t] - hist[t];
        int node = n0 + t;
        if (node < N) rowptr[node] = s + excl;
        hist[t] = s + excl;  // cursor
    }
    if (b == NB - 1 && t == 0) rowptr[N] = E;
    __syncthreads();
    for (int e = s + t; e < e1; e += 256) {
        int2 pr = pairs2[e];
        int li = (unsigned)pr.x >> 17;
        float w = __int_as_float(pr.y);
        int pos = atomicAdd(&hist[li], 1);
        epk[pos] = (unsigned)(pr.x & 0x1FFFF) | (u16f(w) << 17);
        atomicAdd(&wsum[li], w);
    }
    __syncthreads();
    if (t < 128 && n0 + t < N) dis[n0 + t] = rsqrtf(1.0f + wsum[t]);
}

// In-place: epk[e] {f16(w),src} -> {f16(dn*w*dis[src]), src}
__global__ __launch_bounds__(64) void k_norm(const int* __restrict__ rowptr,
                                             unsigned* __restrict__ epk,
                                             const float* __restrict__ dis, int N) {
    int n = blockIdx.x;
    int lane = threadIdx.x;
    float dn = dis[n];
    int e0 = rowptr[n], e1 = rowptr[n + 1];
    for (int e = e0 + lane; e < e1; e += 64) {
        unsigned v = epk[e];
        unsigned src = v & 0x1FFFF;
        float nn = dn * f16u(v >> 17) * dis[src];
        epk[e] = src | (u16f(nn) << 17);
    }
}

// Y[N,128](bf16) = X[N,128](f32) @ W[128,128](f32) via bf16 MFMA.
__global__ __launch_bounds__(512) void k_gemm(const float* __restrict__ X,
                                              const float* __restrict__ W,
                                              unsigned short* __restrict__ Y, int N) {
    __shared__ unsigned short Wt[128 * LDW];
    int tid = threadIdx.x;
    for (int i = tid; i < 4096; i += 512) {  // i indexes float4 of W[k][c]
        float4 v = ((const float4*)W)[i];
        int k = i >> 5;
        int c = (i & 31) * 4;
        Wt[(c + 0) * LDW + k] = f2bf(v.x);
        Wt[(c + 1) * LDW + k] = f2bf(v.y);
        Wt[(c + 2) * LDW + k] = f2bf(v.z);
        Wt[(c + 3) * LDW + k] = f2bf(v.w);
    }
    __syncthreads();
    int w = tid >> 6, lane = tid & 63;
    int l15 = lane & 15, kg = lane >> 4;
    int r = blockIdx.x * 128 + w * 16 + l15;
    f32x4 acc[8];
#pragma unroll
    for (int ct = 0; ct < 8; ++ct) acc[ct] = (f32x4){0.f, 0.f, 0.f, 0.f};
#pragma unroll
    for (int kb = 0; kb < 128; kb += 32) {
        union { unsigned u[4]; bf16x8 v; } a;
        if (r < N) {
            const float4* xp = (const float4*)(X + (size_t)r * CH + kb + kg * 8);
            float4 x0 = xp[0], x1 = xp[1];
            a.u[0] = ((unsigned)f2bf(x0.y) << 16) | f2bf(x0.x);
            a.u[1] = ((unsigned)f2bf(x0.w) << 16) | f2bf(x0.z);
            a.u[2] = ((unsigned)f2bf(x1.y) << 16) | f2bf(x1.x);
            a.u[3] = ((unsigned)f2bf(x1.w) << 16) | f2bf(x1.z);
        } else {
            a.u[0] = a.u[1] = a.u[2] = a.u[3] = 0;
        }
#pragma unroll
        for (int ct = 0; ct < 8; ++ct) {
            bf16x8 b = *(const bf16x8*)&Wt[(ct * 16 + l15) * LDW + kb + kg * 8];
            acc[ct] = __builtin_amdgcn_mfma_f32_16x16x32_bf16(a.v, b, acc[ct], 0, 0, 0);
        }
    }
    int orow = blockIdx.x * 128 + w * 16 + kg * 4;
#pragma unroll
    for (int ct = 0; ct < 8; ++ct) {
#pragma unroll
        for (int j = 0; j < 4; ++j) {
            int rr = orow + j;
            if (rr < N) Y[(size_t)rr * CH + ct * 16 + l15] = f2bf(acc[ct][j]);
        }
    }
}

// One wave per node: out = relu( dn^2*xw[n] + sum_e nn_e*xw[src_e] + b ).
// epk loaded as uint4 (4 edges/load); 16 full-width gathers in flight.
#define GATHER(p) XW[(size_t)((p) & 0x1FFFF) * 64 + lane]
#define ACC4(q, va, vb, vc, vd)                                           \
    {                                                                     \
        float na = f16u((q).x >> 17), nb = f16u((q).y >> 17);             \
        float nc = f16u((q).z >> 17), nd = f16u((q).w >> 17);             \
        ax += na * bflo(va) + nb * bflo(vb) + nc * bflo(vc) + nd * bflo(vd); \
        ay += na * bfhi(va) + nb * bfhi(vb) + nc * bfhi(vc) + nd * bfhi(vd); \
    }
__global__ __launch_bounds__(64) void k_agg(const unsigned int* __restrict__ XW,
                                            const float* __restrict__ dis,
                                            const int* __restrict__ rowptr,
                                            const unsigned* __restrict__ epk,
                                            const float* __restrict__ bias,
                                            float* __restrict__ OUT, int N) {
    int n = blockIdx.x;
    if (n >= N) return;
    int lane = threadIdx.x;
    float dn = dis[n];
    float sn = dn * dn;
    unsigned a = XW[(size_t)n * 64 + lane];
    float ax = bflo(a) * sn;
    float ay = bfhi(a) * sn;
    int e0 = rowptr[n], e1 = rowptr[n + 1];
    int e = e0;
    // scalar head to 4-alignment (epk base is 256B aligned)
    for (; e < e1 && (e & 3); ++e) {
        unsigned p = epk[e];
        unsigned v = GATHER(p);
        float nn = f16u(p >> 17);
        ax += nn * bflo(v);
        ay += nn * bfhi(v);
    }
    // main: 16 edges per iter, 16 gathers in flight
    for (; e + 16 <= e1; e += 16) {
        uint4 q0 = *(const uint4*)&epk[e];
        uint4 q1 = *(const uint4*)&epk[e + 4];
        uint4 q2 = *(const uint4*)&epk[e + 8];
        uint4 q3 = *(const uint4*)&epk[e + 12];
        unsigned v0 = GATHER(q0.x), v1 = GATHER(q0.y), v2 = GATHER(q0.z), v3 = GATHER(q0.w);
        unsigned v4 = GATHER(q1.x), v5 = GATHER(q1.y), v6 = GATHER(q1.z), v7 = GATHER(q1.w);
        unsigned v8 = GATHER(q2.x), v9 = GATHER(q2.y), va = GATHER(q2.z), vb = GATHER(q2.w);
        unsigned vc = GATHER(q3.x), vd = GATHER(q3.y), ve = GATHER(q3.z), vf = GATHER(q3.w);
        ACC4(q0, v0, v1, v2, v3);
        ACC4(q1, v4, v5, v6, v7);
        ACC4(q2, v8, v9, va, vb);
        ACC4(q3, vc, vd, ve, vf);
    }
    // 4-wide
    for (; e + 4 <= e1; e += 4) {
        uint4 q = *(const uint4*)&epk[e];
        unsigned v0 = GATHER(q.x), v1 = GATHER(q.y), v2 = GATHER(q.z), v3 = GATHER(q.w);
        ACC4(q, v0, v1, v2, v3);
    }
    // scalar tail
    for (; e < e1; ++e) {
        unsigned p = epk[e];
        unsigned v = GATHER(p);
        float nn = f16u(p >> 17);
        ax += nn * bflo(v);
        ay += nn * bfhi(v);
    }
    float2 b = ((const float2*)bias)[lane];
    ax = fmaxf(ax + b.x, 0.f);
    ay = fmaxf(ay + b.y, 0.f);
    ((float2*)OUT)[(size_t)n * 64 + lane] = make_float2(ax, ay);
}

__device__ __forceinline__ int lowerb(const int* a, int n, int v) {
    int lo = 0, hi = n;
    while (lo < hi) {
        int m = (lo + hi) >> 1;
        if (a[m] < v) lo = m + 1; else hi = m;
    }
    return lo;
}

// Stage 1: 64 graphs x PCH chunks, partial channel sums.
__global__ __launch_bounds__(128) void k_pool1(const float* __restrict__ H,
                                               const int* __restrict__ batch,
                                               float* __restrict__ partial, int N) {
    __shared__ int ss[2];
    int g = blockIdx.x / PCH;
    int k = blockIdx.x % PCH;
    if (threadIdx.x == 0) {
        ss[0] = lowerb(batch, N, g);
        ss[1] = lowerb(batch, N, g + 1);
    }
    __syncthreads();
    int s = ss[0], len = ss[1] - ss[0];
    int cs = s + (int)(((long long)len * k) / PCH);
    int ce = s + (int)(((long long)len * (k + 1)) / PCH);
    int ch = threadIdx.x;
    float a0 = 0.f, a1 = 0.f;
    int n = cs;
    for (; n + 2 <= ce; n += 2) {
        a0 += H[(size_t)(n + 0) * CH + ch];
        a1 += H[(size_t)(n + 1) * CH + ch];
    }
    for (; n < ce; ++n) a0 += H[(size_t)n * CH + ch];
    partial[(size_t)blockIdx.x * CH + ch] = a0 + a1;
}

// Stage 2: reduce PCH partials per graph, divide by count.
__global__ __launch_bounds__(128) void k_pool2(const float* __restrict__ partial,
                                               const int* __restrict__ batch,
                                               float* __restrict__ P, int N) {
    __shared__ int ss[2];
    int g = blockIdx.x;
    if (threadIdx.x == 0) {
        ss[0] = lowerb(batch, N, g);
        ss[1] = lowerb(batch, N, g + 1);
    }
    __syncthreads();
    int ch = threadIdx.x;
    float a = 0.f;
#pragma unroll
    for (int k = 0; k < PCH; ++k) a += partial[(size_t)(g * PCH + k) * CH + ch];
    float c = (float)(ss[1] - ss[0]);
    P[(size_t)g * CH + ch] = a / fmaxf(c, 1.f);
}

extern "C" void kernel_launch(void* const* d_in, const int* in_sizes, int n_in,
                              void* d_out, int out_size, void* d_ws, size_t ws_size,
                              hipStream_t stream) {
    const float* x     = (const float*)d_in[0];
    const int*   ei    = (const int*)d_in[1];
    const float* ew    = (const float*)d_in[2];
    const int*   batch = (const int*)d_in[3];
    const float* W1    = (const float*)d_in[4];
    const float* b1    = (const float*)d_in[5];
    const float* W2    = (const float*)d_in[6];
    const float* b2    = (const float*)d_in[7];

    int N = in_sizes[0] / CH;   // 50000
    int E = in_sizes[1] / 2;    // 1600000
    const int* row = ei;
    const int* col = ei + E;

    float* out    = (float*)d_out;
    float* h      = out;
    float* pooled = out + (size_t)N * CH;

    int NB    = (N + 127) >> BSH;          // 391
    int chunk = (E + NBLK - 1) / NBLK;     // 1563
    int n2    = NB * NBLK;                 // 400384

    // ws: dis | rowptr | H(n2+1; partial aliases) | bsum(1024)+cnt | epk(E*4) | xw(pairs2 aliases)
    char* wsb = (char*)d_ws;
    size_t oN  = ((size_t)N * 4 + 255) & ~(size_t)255;
    size_t oN1 = ((size_t)(N + 1) * 4 + 255) & ~(size_t)255;
    size_t oH  = ((size_t)(n2 + 1) * 4 + 255) & ~(size_t)255;
    size_t oB  = 8192;
    size_t oE1 = ((size_t)E * 4 + 255) & ~(size_t)255;
    float* dis    = (float*)wsb;
    int*   rowptr = (int*)(wsb + oN);
    int*   H      = (int*)(wsb + oN + oN1);
    int*   bsum   = (int*)(wsb + oN + oN1 + oH);
    int*   cnt    = bsum + 1024;
    unsigned* epk = (unsigned*)(wsb + oN + oN1 + oH + oB);
    unsigned short* xw = (unsigned short*)(wsb + oN + oN1 + oH + oB + oE1);
    int2*  pairs2 = (int2*)xw;     // E*8 = 12.8MB == N*CH*2; dead before k_gemm
    float* partial = (float*)H;    // H dead after sort2; 1MB <= 1.6MB

    int sb2 = (n2 + 1023) / 1024;  // 391

    // ---- CSR build: two-level LDS counting sort (no global atomics) ----
    k_sort1a<<<NBLK, 256, 0, stream>>>(col, H, cnt, E, NB, chunk);
    k_scan1<<<sb2, 1024, 0, stream>>>(H, bsum, cnt, n2, sb2);
    k_sort1b<<<NBLK, 256, 0, stream>>>(row, col, ew, H, bsum, pairs2, E, NB, chunk);
    k_sort2<<<NB, 256, 0, stream>>>(H, bsum, pairs2, epk, rowptr, dis, E, N, NB);
    k_norm<<<N, 64, 0, stream>>>(rowptr, epk, dis, N);

    int gb = (N + 127) / 128;
    // ---- layer 1 ----
    k_gemm<<<gb, 512, 0, stream>>>(x, W1, xw, N);
    k_agg<<<N, 64, 0, stream>>>((const unsigned int*)xw, dis, rowptr, epk, b1, h, N);
    // ---- layer 2 ----
    k_gemm<<<gb, 512, 0, stream>>>(h, W2, xw, N);
    k_agg<<<N, 64, 0, stream>>>((const unsigned int*)xw, dis, rowptr, epk, b2, h, N);
    // ---- mean pool (two-stage) ----
    k_pool1<<<64 * PCH, 128, 0, stream>>>(h, batch, partial, N);
    k_pool2<<<64, 128, 0, stream>>>(partial, batch, pooled, N);
}

// Round 12
// 232.414 us; speedup vs baseline: 1.4766x; 1.0056x over previous
//
#include <hip/hip_runtime.h>
#include <hip/hip_fp16.h>

// GCNEncoder: two GCNConv(+relu) layers + global mean pool.
// N=50000 nodes, E=1.6M edges, 128 ch, 64 graphs.
// R12: norm factored away (xw' = dis[r]*(X@W)[r] scaled in GEMM epilogue;
// k_agg uses raw f16(w) from sort2; final dn scale once per node). k_norm
// deleted. h1 stored bf16 (identical numerics; gemm2 reads bf16 directly).
// k_agg: 4 nodes/block for occupancy. k_agg itself is at its structural
// roofline (R10/R11: FETCH-bound at ~3.3TB/s, insensitive to MLP/width).

#define CH 128
#define BSH 7         // 128 nodes per bucket
#define NBLK 1024     // level-1 edge-chunk blocks
#define MAXNB 512     // LDS histogram capacity (NB = ceil(N/128) = 391)
#define PCH 32        // pool chunks per graph
#define LDW 136       // Wt LDS stride

typedef __attribute__((ext_vector_type(8))) short bf16x8;
typedef __attribute__((ext_vector_type(4))) float f32x4;

static __device__ __forceinline__ unsigned short f2bf(float f) {
    unsigned u = __float_as_uint(f);
    unsigned r = (u + 0x7FFF + ((u >> 16) & 1)) >> 16;  // RNE
    return (unsigned short)r;
}
static __device__ __forceinline__ float bflo(unsigned v) { return __uint_as_float(v << 16); }
static __device__ __forceinline__ float bfhi(unsigned v) { return __uint_as_float(v & 0xFFFF0000u); }
static __device__ __forceinline__ float f16u(unsigned bits15) {
    __half_raw hr; hr.x = (unsigned short)(bits15 & 0x7FFF);
    return __half2float(*reinterpret_cast<__half*>(&hr));
}
static __device__ __forceinline__ unsigned u16f(float f) {  // f >= 0
    __half hh = __float2half(f);
    return (unsigned)(*reinterpret_cast<unsigned short*>(&hh)) & 0x7FFF;
}

// ---- level-1 count: per-(bucket, chunk-block) histogram, LDS atomics only
__global__ __launch_bounds__(256) void k_sort1a(const int* __restrict__ col,
                                                int* __restrict__ H, int* __restrict__ cnt,
                                                int E, int NB, int chunk) {
    __shared__ int hist[MAXNB];
    int t = threadIdx.x, blk = blockIdx.x;
    if (blk == 0 && t == 0) *cnt = 0;  // reset scan1's last-block counter
    for (int i = t; i < NB; i += 256) hist[i] = 0;
    __syncthreads();
    int s = blk * chunk, e1 = min(s + chunk, E);
    for (int e = s + t; e < e1; e += 256) atomicAdd(&hist[col[e] >> BSH], 1);
    __syncthreads();
    for (int i = t; i < NB; i += 256) H[(size_t)i * NBLK + blk] = hist[i];
}

// ---- scan: block-local exclusive in place + last block scans bsum (fused phase 2)
__global__ __launch_bounds__(1024) void k_scan1(int* __restrict__ data,
                                                int* __restrict__ bsum,
                                                int* __restrict__ cnt, int n, int nb) {
    __shared__ int sd[1024];
    __shared__ int lastFlag;
    int t = threadIdx.x;
    int i = blockIdx.x * 1024 + t;
    int v = (i < n) ? data[i] : 0;
    sd[t] = v;
    __syncthreads();
    for (int off = 1; off < 1024; off <<= 1) {
        int u = (t >= off) ? sd[t - off] : 0;
        __syncthreads();
        sd[t] += u;
        __syncthreads();
    }
    if (i < n) data[i] = sd[t] - v;
    if (t == 1023) {
        bsum[blockIdx.x] = sd[1023];
        __threadfence();
        lastFlag = (atomicAdd(cnt, 1) == (int)gridDim.x - 1);
    }
    __syncthreads();
    if (lastFlag) {
        __threadfence();
        int v2 = (t < nb) ? bsum[t] : 0;
        sd[t] = v2;
        __syncthreads();
        for (int off = 1; off < 1024; off <<= 1) {
            int u = (t >= off) ? sd[t - off] : 0;
            __syncthreads();
            sd[t] += u;
            __syncthreads();
        }
        if (t < nb) bsum[t] = sd[t] - v2;
    }
}

// ---- level-1 scatter into bucket order via LDS cursors (disjoint regions)
__global__ __launch_bounds__(256) void k_sort1b(const int* __restrict__ row,
                                                const int* __restrict__ col,
                                                const float* __restrict__ ew,
                                                const int* __restrict__ Hs,
                                                const int* __restrict__ bsum,
                                                int2* __restrict__ pairs2,
                                                int E, int NB, int chunk) {
    __shared__ int cur[MAXNB];
    int t = threadIdx.x, blk = blockIdx.x;
    for (int i = t; i < NB; i += 256) cur[i] = Hs[(size_t)i * NBLK + blk] + bsum[i];
    __syncthreads();
    int s = blk * chunk, e1 = min(s + chunk, E);
    for (int e = s + t; e < e1; e += 256) {
        int c = col[e];
        int pos = atomicAdd(&cur[c >> BSH], 1);
        pairs2[pos] = make_int2(row[e] | ((c & 127) << 17), __float_as_int(ew[e]));
    }
}

// ---- level-2: per-bucket node sort + rowptr + degree (dis), LDS only.
// Output: epk[pos] = { f16(w):15 | src:17 } (4B per edge) — final form, no norm pass.
__global__ __launch_bounds__(256) void k_sort2(const int* __restrict__ Hs,
                                               const int* __restrict__ bsum,
                                               const int2* __restrict__ pairs2,
                                               unsigned* __restrict__ epk,
                                               int* __restrict__ rowptr,
                                               float* __restrict__ dis,
                                               int E, int N, int NB) {
    __shared__ int hist[128];
    __shared__ int pref[128];
    __shared__ float wsum[128];
    int b = blockIdx.x, t = threadIdx.x;
    int n0 = b << BSH;
    int s = Hs[(size_t)b * NBLK] + bsum[b];
    int e1 = (b + 1 < NB) ? Hs[(size_t)(b + 1) * NBLK] + bsum[b + 1] : E;
    if (t < 128) { hist[t] = 0; wsum[t] = 0.f; }
    __syncthreads();
    for (int e = s + t; e < e1; e += 256)
        atomicAdd(&hist[(unsigned)pairs2[e].x >> 17], 1);
    __syncthreads();
    if (t < 128) pref[t] = hist[t];
    __syncthreads();
    for (int off = 1; off < 128; off <<= 1) {
        int v = 0;
        if (t < 128 && t >= off) v = pref[t - off];
        __syncthreads();
        if (t < 128) pref[t] += v;
        __syncthreads();
    }
    if (t < 128) {
        int excl = pref[t] - hist[t];
        int node = n0 + t;
        if (node < N) rowptr[node] = s + excl;
        hist[t] = s + excl;  // cursor
    }
    if (b == NB - 1 && t == 0) rowptr[N] = E;
    __syncthreads();
    for (int e = s + t; e < e1; e += 256) {
        int2 pr = pairs2[e];
        int li = (unsigned)pr.x >> 17;
        float w = __int_as_float(pr.y);
        int pos = atomicAdd(&hist[li], 1);
        epk[pos] = (unsigned)(pr.x & 0x1FFFF) | (u16f(w) << 17);
        atomicAdd(&wsum[li], w);
    }
    __syncthreads();
    if (t < 128 && n0 + t < N) dis[n0 + t] = rsqrtf(1.0f + wsum[t]);
}

// Y[N,128](bf16) = dis[r] * (X[N,128](f32) @ W) via bf16 MFMA.
__global__ __launch_bounds__(512) void k_gemm_f32(const float* __restrict__ X,
                                                  const float* __restrict__ W,
                                                  const float* __restrict__ dis,
                                                  unsigned short* __restrict__ Y, int N) {
    __shared__ unsigned short Wt[128 * LDW];
    int tid = threadIdx.x;
    for (int i = tid; i < 4096; i += 512) {  // i indexes float4 of W[k][c]
        float4 v = ((const float4*)W)[i];
        int k = i >> 5;
        int c = (i & 31) * 4;
        Wt[(c + 0) * LDW + k] = f2bf(v.x);
        Wt[(c + 1) * LDW + k] = f2bf(v.y);
        Wt[(c + 2) * LDW + k] = f2bf(v.z);
        Wt[(c + 3) * LDW + k] = f2bf(v.w);
    }
    __syncthreads();
    int w = tid >> 6, lane = tid & 63;
    int l15 = lane & 15, kg = lane >> 4;
    int r = blockIdx.x * 128 + w * 16 + l15;
    f32x4 acc[8];
#pragma unroll
    for (int ct = 0; ct < 8; ++ct) acc[ct] = (f32x4){0.f, 0.f, 0.f, 0.f};
#pragma unroll
    for (int kb = 0; kb < 128; kb += 32) {
        union { unsigned u[4]; bf16x8 v; } a;
        if (r < N) {
            const float4* xp = (const float4*)(X + (size_t)r * CH + kb + kg * 8);
            float4 x0 = xp[0], x1 = xp[1];
            a.u[0] = ((unsigned)f2bf(x0.y) << 16) | f2bf(x0.x);
            a.u[1] = ((unsigned)f2bf(x0.w) << 16) | f2bf(x0.z);
            a.u[2] = ((unsigned)f2bf(x1.y) << 16) | f2bf(x1.x);
            a.u[3] = ((unsigned)f2bf(x1.w) << 16) | f2bf(x1.z);
        } else {
            a.u[0] = a.u[1] = a.u[2] = a.u[3] = 0;
        }
#pragma unroll
        for (int ct = 0; ct < 8; ++ct) {
            bf16x8 b = *(const bf16x8*)&Wt[(ct * 16 + l15) * LDW + kb + kg * 8];
            acc[ct] = __builtin_amdgcn_mfma_f32_16x16x32_bf16(a.v, b, acc[ct], 0, 0, 0);
        }
    }
    int orow = blockIdx.x * 128 + w * 16 + kg * 4;
    float dv[4];
#pragma unroll
    for (int j = 0; j < 4; ++j) dv[j] = (orow + j < N) ? dis[orow + j] : 0.f;
#pragma unroll
    for (int ct = 0; ct < 8; ++ct) {
#pragma unroll
        for (int j = 0; j < 4; ++j) {
            int rr = orow + j;
            if (rr < N) Y[(size_t)rr * CH + ct * 16 + l15] = f2bf(acc[ct][j] * dv[j]);
        }
    }
}

// Y[N,128](bf16) = dis[r] * (Xb[N,128](bf16) @ W) via bf16 MFMA.
__global__ __launch_bounds__(512) void k_gemm_bf16(const unsigned short* __restrict__ Xb,
                                                   const float* __restrict__ W,
                                                   const float* __restrict__ dis,
                                                   unsigned short* __restrict__ Y, int N) {
    __shared__ unsigned short Wt[128 * LDW];
    int tid = threadIdx.x;
    for (int i = tid; i < 4096; i += 512) {
        float4 v = ((const float4*)W)[i];
        int k = i >> 5;
        int c = (i & 31) * 4;
        Wt[(c + 0) * LDW + k] = f2bf(v.x);
        Wt[(c + 1) * LDW + k] = f2bf(v.y);
        Wt[(c + 2) * LDW + k] = f2bf(v.z);
        Wt[(c + 3) * LDW + k] = f2bf(v.w);
    }
    __syncthreads();
    int w = tid >> 6, lane = tid & 63;
    int l15 = lane & 15, kg = lane >> 4;
    int r = blockIdx.x * 128 + w * 16 + l15;
    f32x4 acc[8];
#pragma unroll
    for (int ct = 0; ct < 8; ++ct) acc[ct] = (f32x4){0.f, 0.f, 0.f, 0.f};
#pragma unroll
    for (int kb = 0; kb < 128; kb += 32) {
        bf16x8 a;
        if (r < N) {
            a = *(const bf16x8*)&Xb[(size_t)r * CH + kb + kg * 8];
        } else {
            a = (bf16x8){0, 0, 0, 0, 0, 0, 0, 0};
        }
#pragma unroll
        for (int ct = 0; ct < 8; ++ct) {
            bf16x8 b = *(const bf16x8*)&Wt[(ct * 16 + l15) * LDW + kb + kg * 8];
            acc[ct] = __builtin_amdgcn_mfma_f32_16x16x32_bf16(a, b, acc[ct], 0, 0, 0);
        }
    }
    int orow = blockIdx.x * 128 + w * 16 + kg * 4;
    float dv[4];
#pragma unroll
    for (int j = 0; j < 4; ++j) dv[j] = (orow + j < N) ? dis[orow + j] : 0.f;
#pragma unroll
    for (int ct = 0; ct < 8; ++ct) {
#pragma unroll
        for (int j = 0; j < 4; ++j) {
            int rr = orow + j;
            if (rr < N) Y[(size_t)rr * CH + ct * 16 + l15] = f2bf(acc[ct][j] * dv[j]);
        }
    }
}

// Wave per node (4 waves/block): sum = xw'[n] + sum_e w_e * xw'[src_e];
// out = relu(dn*sum + b). xw' rows pre-scaled by dis. 16 gathers in flight.
#define GATHER(p) XW[(size_t)((p) & 0x1FFFF) * 64 + lane]
#define ACC4(q, va, vb, vc, vd)                                              \
    {                                                                        \
        float na = f16u((q).x >> 17), nb = f16u((q).y >> 17);                \
        float nc = f16u((q).z >> 17), nd = f16u((q).w >> 17);                \
        ax += na * bflo(va) + nb * bflo(vb) + nc * bflo(vc) + nd * bflo(vd); \
        ay += na * bfhi(va) + nb * bfhi(vb) + nc * bfhi(vc) + nd * bfhi(vd); \
    }
template <bool OUT_BF16>
__global__ __launch_bounds__(256) void k_agg(const unsigned int* __restrict__ XW,
                                             const float* __restrict__ dis,
                                             const int* __restrict__ rowptr,
                                             const unsigned* __restrict__ epk,
                                             const float* __restrict__ bias,
                                             void* __restrict__ OUT, int N) {
    int n = blockIdx.x * 4 + (threadIdx.x >> 6);
    if (n >= N) return;
    int lane = threadIdx.x & 63;
    unsigned a = XW[(size_t)n * 64 + lane];
    float ax = bflo(a);
    float ay = bfhi(a);
    int e0 = rowptr[n], e1 = rowptr[n + 1];
    int e = e0;
    for (; e < e1 && (e & 3); ++e) {
        unsigned p = epk[e];
        unsigned v = GATHER(p);
        float nn = f16u(p >> 17);
        ax += nn * bflo(v);
        ay += nn * bfhi(v);
    }
    for (; e + 16 <= e1; e += 16) {
        uint4 q0 = *(const uint4*)&epk[e];
        uint4 q1 = *(const uint4*)&epk[e + 4];
        uint4 q2 = *(const uint4*)&epk[e + 8];
        uint4 q3 = *(const uint4*)&epk[e + 12];
        unsigned v0 = GATHER(q0.x), v1 = GATHER(q0.y), v2 = GATHER(q0.z), v3 = GATHER(q0.w);
        unsigned v4 = GATHER(q1.x), v5 = GATHER(q1.y), v6 = GATHER(q1.z), v7 = GATHER(q1.w);
        unsigned v8 = GATHER(q2.x), v9 = GATHER(q2.y), va = GATHER(q2.z), vb = GATHER(q2.w);
        unsigned vc = GATHER(q3.x), vd = GATHER(q3.y), ve = GATHER(q3.z), vf = GATHER(q3.w);
        ACC4(q0, v0, v1, v2, v3);
        ACC4(q1, v4, v5, v6, v7);
        ACC4(q2, v8, v9, va, vb);
        ACC4(q3, vc, vd, ve, vf);
    }
    for (; e + 4 <= e1; e += 4) {
        uint4 q = *(const uint4*)&epk[e];
        unsigned v0 = GATHER(q.x), v1 = GATHER(q.y), v2 = GATHER(q.z), v3 = GATHER(q.w);
        ACC4(q, v0, v1, v2, v3);
    }
    for (; e < e1; ++e) {
        unsigned p = epk[e];
        unsigned v = GATHER(p);
        float nn = f16u(p >> 17);
        ax += nn * bflo(v);
        ay += nn * bfhi(v);
    }
    float dn = dis[n];
    float2 b = ((const float2*)bias)[lane];
    ax = fmaxf(fmaf(dn, ax, b.x), 0.f);
    ay = fmaxf(fmaf(dn, ay, b.y), 0.f);
    if (OUT_BF16) {
        unsigned o = ((unsigned)f2bf(ay) << 16) | f2bf(ax);
        ((unsigned*)OUT)[(size_t)n * 64 + lane] = o;
    } else {
        ((float2*)OUT)[(size_t)n * 64 + lane] = make_float2(ax, ay);
    }
}

__device__ __forceinline__ int lowerb(const int* a, int n, int v) {
    int lo = 0, hi = n;
    while (lo < hi) {
        int m = (lo + hi) >> 1;
        if (a[m] < v) lo = m + 1; else hi = m;
    }
    return lo;
}

// Stage 1: 64 graphs x PCH chunks, partial channel sums.
__global__ __launch_bounds__(128) void k_pool1(const float* __restrict__ H,
                                               const int* __restrict__ batch,
                                               float* __restrict__ partial, int N) {
    __shared__ int ss[2];
    int g = blockIdx.x / PCH;
    int k = blockIdx.x % PCH;
    if (threadIdx.x == 0) {
        ss[0] = lowerb(batch, N, g);
        ss[1] = lowerb(batch, N, g + 1);
    }
    __syncthreads();
    int s = ss[0], len = ss[1] - ss[0];
    int cs = s + (int)(((long long)len * k) / PCH);
    int ce = s + (int)(((long long)len * (k + 1)) / PCH);
    int ch = threadIdx.x;
    float a0 = 0.f, a1 = 0.f;
    int n = cs;
    for (; n + 2 <= ce; n += 2) {
        a0 += H[(size_t)(n + 0) * CH + ch];
        a1 += H[(size_t)(n + 1) * CH + ch];
    }
    for (; n < ce; ++n) a0 += H[(size_t)n * CH + ch];
    partial[(size_t)blockIdx.x * CH + ch] = a0 + a1;
}

// Stage 2: reduce PCH partials per graph, divide by count.
__global__ __launch_bounds__(128) void k_pool2(const float* __restrict__ partial,
                                               const int* __restrict__ batch,
                                               float* __restrict__ P, int N) {
    __shared__ int ss[2];
    int g = blockIdx.x;
    if (threadIdx.x == 0) {
        ss[0] = lowerb(batch, N, g);
        ss[1] = lowerb(batch, N, g + 1);
    }
    __syncthreads();
    int ch = threadIdx.x;
    float a = 0.f;
#pragma unroll
    for (int k = 0; k < PCH; ++k) a += partial[(size_t)(g * PCH + k) * CH + ch];
    float c = (float)(ss[1] - ss[0]);
    P[(size_t)g * CH + ch] = a / fmaxf(c, 1.f);
}

extern "C" void kernel_launch(void* const* d_in, const int* in_sizes, int n_in,
                              void* d_out, int out_size, void* d_ws, size_t ws_size,
                              hipStream_t stream) {
    const float* x     = (const float*)d_in[0];
    const int*   ei    = (const int*)d_in[1];
    const float* ew    = (const float*)d_in[2];
    const int*   batch = (const int*)d_in[3];
    const float* W1    = (const float*)d_in[4];
    const float* b1    = (const float*)d_in[5];
    const float* W2    = (const float*)d_in[6];
    const float* b2    = (const float*)d_in[7];

    int N = in_sizes[0] / CH;   // 50000
    int E = in_sizes[1] / 2;    // 1600000
    const int* row = ei;
    const int* col = ei + E;

    float* out    = (float*)d_out;
    float* h      = out;
    float* pooled = out + (size_t)N * CH;

    int NB    = (N + 127) >> BSH;          // 391
    int chunk = (E + NBLK - 1) / NBLK;     // 1563
    int n2    = NB * NBLK;                 // 400384

    // ws: dis | rowptr | H(n2+1; partial aliases) | bsum+cnt | epk | bufA | bufB
    // bufA: pairs2 -> xw'(L1) -> xw'(L2).  bufB: h1 (bf16).
    char* wsb = (char*)d_ws;
    size_t oN  = ((size_t)N * 4 + 255) & ~(size_t)255;
    size_t oN1 = ((size_t)(N + 1) * 4 + 255) & ~(size_t)255;
    size_t oH  = ((size_t)(n2 + 1) * 4 + 255) & ~(size_t)255;
    size_t oB  = 8192;
    size_t oE1 = ((size_t)E * 4 + 255) & ~(size_t)255;
    size_t oE2 = ((size_t)E * 8 + 255) & ~(size_t)255;  // 12.8MB (>= N*CH*2)
    float* dis    = (float*)wsb;
    int*   rowptr = (int*)(wsb + oN);
    int*   H      = (int*)(wsb + oN + oN1);
    int*   bsum   = (int*)(wsb + oN + oN1 + oH);
    int*   cnt    = bsum + 1024;
    unsigned* epk = (unsigned*)(wsb + oN + oN1 + oH + oB);
    char*  bufA   = wsb + oN + oN1 + oH + oB + oE1;
    char*  bufB   = bufA + oE2;
    int2*  pairs2 = (int2*)bufA;
    unsigned short* xw = (unsigned short*)bufA;
    unsigned short* h1 = (unsigned short*)bufB;
    float* partial = (float*)H;    // H dead after sort2; 1MB <= 1.6MB

    int sb2 = (n2 + 1023) / 1024;  // 391

    // ---- CSR build: two-level LDS counting sort (no global atomics) ----
    k_sort1a<<<NBLK, 256, 0, stream>>>(col, H, cnt, E, NB, chunk);
    k_scan1<<<sb2, 1024, 0, stream>>>(H, bsum, cnt, n2, sb2);
    k_sort1b<<<NBLK, 256, 0, stream>>>(row, col, ew, H, bsum, pairs2, E, NB, chunk);
    k_sort2<<<NB, 256, 0, stream>>>(H, bsum, pairs2, epk, rowptr, dis, E, N, NB);

    int gb = (N + 127) / 128;
    int ab = (N + 3) / 4;
    // ---- layer 1 ----
    k_gemm_f32<<<gb, 512, 0, stream>>>(x, W1, dis, xw, N);
    k_agg<true><<<ab, 256, 0, stream>>>((const unsigned int*)xw, dis, rowptr, epk, b1, h1, N);
    // ---- layer 2 ----
    k_gemm_bf16<<<gb, 512, 0, stream>>>(h1, W2, dis, xw, N);
    k_agg<false><<<ab, 256, 0, stream>>>((const unsigned int*)xw, dis, rowptr, epk, b2, h, N);
    // ---- mean pool (two-stage) ----
    k_pool1<<<64 * PCH, 128, 0, stream>>>(h, batch, partial, N);
    k_pool2<<<64, 128, 0, stream>>>(partial, batch, pooled, N);
}

// Round 13
// 225.330 us; speedup vs baseline: 1.5230x; 1.0314x over previous
//
#include <hip/hip_runtime.h>
#include <hip/hip_fp16.h>

// GCNEncoder: two GCNConv(+relu) layers + global mean pool.
// N=50000 nodes, E=1.6M edges, 128 ch, 64 graphs.
// R13: revert k_agg to 1-wave/1-node blocks (R12's 4-node blocks coupled
// waves to the block's max-degree node: VALUBusy 31->47%, +9% dur).
// Keep R12 fusions: factored norm (no k_norm), bf16 h1, fused scan.
// epk edge stream loaded nontemporally (read-once; don't evict xw from L2).

#define CH 128
#define BSH 7         // 128 nodes per bucket
#define NBLK 1024     // level-1 edge-chunk blocks
#define MAXNB 512     // LDS histogram capacity (NB = ceil(N/128) = 391)
#define PCH 32        // pool chunks per graph
#define LDW 136       // Wt LDS stride

typedef __attribute__((ext_vector_type(8))) short bf16x8;
typedef __attribute__((ext_vector_type(4))) float f32x4;
typedef __attribute__((ext_vector_type(4))) unsigned uintx4;

static __device__ __forceinline__ unsigned short f2bf(float f) {
    unsigned u = __float_as_uint(f);
    unsigned r = (u + 0x7FFF + ((u >> 16) & 1)) >> 16;  // RNE
    return (unsigned short)r;
}
static __device__ __forceinline__ float bflo(unsigned v) { return __uint_as_float(v << 16); }
static __device__ __forceinline__ float bfhi(unsigned v) { return __uint_as_float(v & 0xFFFF0000u); }
static __device__ __forceinline__ float f16u(unsigned bits15) {
    __half_raw hr; hr.x = (unsigned short)(bits15 & 0x7FFF);
    return __half2float(*reinterpret_cast<__half*>(&hr));
}
static __device__ __forceinline__ unsigned u16f(float f) {  // f >= 0
    __half hh = __float2half(f);
    return (unsigned)(*reinterpret_cast<unsigned short*>(&hh)) & 0x7FFF;
}

// ---- level-1 count: per-(bucket, chunk-block) histogram, LDS atomics only
__global__ __launch_bounds__(256) void k_sort1a(const int* __restrict__ col,
                                                int* __restrict__ H, int* __restrict__ cnt,
                                                int E, int NB, int chunk) {
    __shared__ int hist[MAXNB];
    int t = threadIdx.x, blk = blockIdx.x;
    if (blk == 0 && t == 0) *cnt = 0;  // reset scan1's last-block counter
    for (int i = t; i < NB; i += 256) hist[i] = 0;
    __syncthreads();
    int s = blk * chunk, e1 = min(s + chunk, E);
    for (int e = s + t; e < e1; e += 256) atomicAdd(&hist[col[e] >> BSH], 1);
    __syncthreads();
    for (int i = t; i < NB; i += 256) H[(size_t)i * NBLK + blk] = hist[i];
}

// ---- scan: block-local exclusive in place + last block scans bsum (fused phase 2)
__global__ __launch_bounds__(1024) void k_scan1(int* __restrict__ data,
                                                int* __restrict__ bsum,
                                                int* __restrict__ cnt, int n, int nb) {
    __shared__ int sd[1024];
    __shared__ int lastFlag;
    int t = threadIdx.x;
    int i = blockIdx.x * 1024 + t;
    int v = (i < n) ? data[i] : 0;
    sd[t] = v;
    __syncthreads();
    for (int off = 1; off < 1024; off <<= 1) {
        int u = (t >= off) ? sd[t - off] : 0;
        __syncthreads();
        sd[t] += u;
        __syncthreads();
    }
    if (i < n) data[i] = sd[t] - v;
    if (t == 1023) {
        bsum[blockIdx.x] = sd[1023];
        __threadfence();
        lastFlag = (atomicAdd(cnt, 1) == (int)gridDim.x - 1);
    }
    __syncthreads();
    if (lastFlag) {
        __threadfence();
        int v2 = (t < nb) ? bsum[t] : 0;
        sd[t] = v2;
        __syncthreads();
        for (int off = 1; off < 1024; off <<= 1) {
            int u = (t >= off) ? sd[t - off] : 0;
            __syncthreads();
            sd[t] += u;
            __syncthreads();
        }
        if (t < nb) bsum[t] = sd[t] - v2;
    }
}

// ---- level-1 scatter into bucket order via LDS cursors (disjoint regions)
__global__ __launch_bounds__(256) void k_sort1b(const int* __restrict__ row,
                                                const int* __restrict__ col,
                                                const float* __restrict__ ew,
                                                const int* __restrict__ Hs,
                                                const int* __restrict__ bsum,
                                                int2* __restrict__ pairs2,
                                                int E, int NB, int chunk) {
    __shared__ int cur[MAXNB];
    int t = threadIdx.x, blk = blockIdx.x;
    for (int i = t; i < NB; i += 256) cur[i] = Hs[(size_t)i * NBLK + blk] + bsum[i];
    __syncthreads();
    int s = blk * chunk, e1 = min(s + chunk, E);
    for (int e = s + t; e < e1; e += 256) {
        int c = col[e];
        int pos = atomicAdd(&cur[c >> BSH], 1);
        pairs2[pos] = make_int2(row[e] | ((c & 127) << 17), __float_as_int(ew[e]));
    }
}

// ---- level-2: per-bucket node sort + rowptr + degree (dis), LDS only.
// Output: epk[pos] = { f16(w):15 | src:17 } (4B per edge) — final form.
__global__ __launch_bounds__(256) void k_sort2(const int* __restrict__ Hs,
                                               const int* __restrict__ bsum,
                                               const int2* __restrict__ pairs2,
                                               unsigned* __restrict__ epk,
                                               int* __restrict__ rowptr,
                                               float* __restrict__ dis,
                                               int E, int N, int NB) {
    __shared__ int hist[128];
    __shared__ int pref[128];
    __shared__ float wsum[128];
    int b = blockIdx.x, t = threadIdx.x;
    int n0 = b << BSH;
    int s = Hs[(size_t)b * NBLK] + bsum[b];
    int e1 = (b + 1 < NB) ? Hs[(size_t)(b + 1) * NBLK] + bsum[b + 1] : E;
    if (t < 128) { hist[t] = 0; wsum[t] = 0.f; }
    __syncthreads();
    for (int e = s + t; e < e1; e += 256)
        atomicAdd(&hist[(unsigned)pairs2[e].x >> 17], 1);
    __syncthreads();
    if (t < 128) pref[t] = hist[t];
    __syncthreads();
    for (int off = 1; off < 128; off <<= 1) {
        int v = 0;
        if (t < 128 && t >= off) v = pref[t - off];
        __syncthreads();
        if (t < 128) pref[t] += v;
        __syncthreads();
    }
    if (t < 128) {
        int excl = pref[t] - hist[t];
        int node = n0 + t;
        if (node < N) rowptr[node] = s + excl;
        hist[t] = s + excl;  // cursor
    }
    if (b == NB - 1 && t == 0) rowptr[N] = E;
    __syncthreads();
    for (int e = s + t; e < e1; e += 256) {
        int2 pr = pairs2[e];
        int li = (unsigned)pr.x >> 17;
        float w = __int_as_float(pr.y);
        int pos = atomicAdd(&hist[li], 1);
        epk[pos] = (unsigned)(pr.x & 0x1FFFF) | (u16f(w) << 17);
        atomicAdd(&wsum[li], w);
    }
    __syncthreads();
    if (t < 128 && n0 + t < N) dis[n0 + t] = rsqrtf(1.0f + wsum[t]);
}

// Y[N,128](bf16) = dis[r] * (X[N,128](f32) @ W) via bf16 MFMA.
__global__ __launch_bounds__(512) void k_gemm_f32(const float* __restrict__ X,
                                                  const float* __restrict__ W,
                                                  const float* __restrict__ dis,
                                                  unsigned short* __restrict__ Y, int N) {
    __shared__ unsigned short Wt[128 * LDW];
    int tid = threadIdx.x;
    for (int i = tid; i < 4096; i += 512) {  // i indexes float4 of W[k][c]
        float4 v = ((const float4*)W)[i];
        int k = i >> 5;
        int c = (i & 31) * 4;
        Wt[(c + 0) * LDW + k] = f2bf(v.x);
        Wt[(c + 1) * LDW + k] = f2bf(v.y);
        Wt[(c + 2) * LDW + k] = f2bf(v.z);
        Wt[(c + 3) * LDW + k] = f2bf(v.w);
    }
    __syncthreads();
    int w = tid >> 6, lane = tid & 63;
    int l15 = lane & 15, kg = lane >> 4;
    int r = blockIdx.x * 128 + w * 16 + l15;
    f32x4 acc[8];
#pragma unroll
    for (int ct = 0; ct < 8; ++ct) acc[ct] = (f32x4){0.f, 0.f, 0.f, 0.f};
#pragma unroll
    for (int kb = 0; kb < 128; kb += 32) {
        union { unsigned u[4]; bf16x8 v; } a;
        if (r < N) {
            const float4* xp = (const float4*)(X + (size_t)r * CH + kb + kg * 8);
            float4 x0 = xp[0], x1 = xp[1];
            a.u[0] = ((unsigned)f2bf(x0.y) << 16) | f2bf(x0.x);
            a.u[1] = ((unsigned)f2bf(x0.w) << 16) | f2bf(x0.z);
            a.u[2] = ((unsigned)f2bf(x1.y) << 16) | f2bf(x1.x);
            a.u[3] = ((unsigned)f2bf(x1.w) << 16) | f2bf(x1.z);
        } else {
            a.u[0] = a.u[1] = a.u[2] = a.u[3] = 0;
        }
#pragma unroll
        for (int ct = 0; ct < 8; ++ct) {
            bf16x8 b = *(const bf16x8*)&Wt[(ct * 16 + l15) * LDW + kb + kg * 8];
            acc[ct] = __builtin_amdgcn_mfma_f32_16x16x32_bf16(a.v, b, acc[ct], 0, 0, 0);
        }
    }
    int orow = blockIdx.x * 128 + w * 16 + kg * 4;
    float dv[4];
#pragma unroll
    for (int j = 0; j < 4; ++j) dv[j] = (orow + j < N) ? dis[orow + j] : 0.f;
#pragma unroll
    for (int ct = 0; ct < 8; ++ct) {
#pragma unroll
        for (int j = 0; j < 4; ++j) {
            int rr = orow + j;
            if (rr < N) Y[(size_t)rr * CH + ct * 16 + l15] = f2bf(acc[ct][j] * dv[j]);
        }
    }
}

// Y[N,128](bf16) = dis[r] * (Xb[N,128](bf16) @ W) via bf16 MFMA.
__global__ __launch_bounds__(512) void k_gemm_bf16(const unsigned short* __restrict__ Xb,
                                                   const float* __restrict__ W,
                                                   const float* __restrict__ dis,
                                                   unsigned short* __restrict__ Y, int N) {
    __shared__ unsigned short Wt[128 * LDW];
    int tid = threadIdx.x;
    for (int i = tid; i < 4096; i += 512) {
        float4 v = ((const float4*)W)[i];
        int k = i >> 5;
        int c = (i & 31) * 4;
        Wt[(c + 0) * LDW + k] = f2bf(v.x);
        Wt[(c + 1) * LDW + k] = f2bf(v.y);
        Wt[(c + 2) * LDW + k] = f2bf(v.z);
        Wt[(c + 3) * LDW + k] = f2bf(v.w);
    }
    __syncthreads();
    int w = tid >> 6, lane = tid & 63;
    int l15 = lane & 15, kg = lane >> 4;
    int r = blockIdx.x * 128 + w * 16 + l15;
    f32x4 acc[8];
#pragma unroll
    for (int ct = 0; ct < 8; ++ct) acc[ct] = (f32x4){0.f, 0.f, 0.f, 0.f};
#pragma unroll
    for (int kb = 0; kb < 128; kb += 32) {
        bf16x8 a;
        if (r < N) {
            a = *(const bf16x8*)&Xb[(size_t)r * CH + kb + kg * 8];
        } else {
            a = (bf16x8){0, 0, 0, 0, 0, 0, 0, 0};
        }
#pragma unroll
        for (int ct = 0; ct < 8; ++ct) {
            bf16x8 b = *(const bf16x8*)&Wt[(ct * 16 + l15) * LDW + kb + kg * 8];
            acc[ct] = __builtin_amdgcn_mfma_f32_16x16x32_bf16(a, b, acc[ct], 0, 0, 0);
        }
    }
    int orow = blockIdx.x * 128 + w * 16 + kg * 4;
    float dv[4];
#pragma unroll
    for (int j = 0; j < 4; ++j) dv[j] = (orow + j < N) ? dis[orow + j] : 0.f;
#pragma unroll
    for (int ct = 0; ct < 8; ++ct) {
#pragma unroll
        for (int j = 0; j < 4; ++j) {
            int rr = orow + j;
            if (rr < N) Y[(size_t)rr * CH + ct * 16 + l15] = f2bf(acc[ct][j] * dv[j]);
        }
    }
}

// One wave per node: sum = xw'[n] + sum_e w_e * xw'[src_e]; out = relu(dn*sum + b).
// xw' rows pre-scaled by dis (factored norm). 16 gathers in flight; epk nontemporal.
#define GATHER(p) XW[(size_t)((p) & 0x1FFFF) * 64 + lane]
#define ACC4(q, va, vb, vc, vd)                                              \
    {                                                                        \
        float na = f16u((q)[0] >> 17), nb = f16u((q)[1] >> 17);              \
        float nc = f16u((q)[2] >> 17), nd = f16u((q)[3] >> 17);              \
        ax += na * bflo(va) + nb * bflo(vb) + nc * bflo(vc) + nd * bflo(vd); \
        ay += na * bfhi(va) + nb * bfhi(vb) + nc * bfhi(vc) + nd * bfhi(vd); \
    }
template <bool OUT_BF16>
__global__ __launch_bounds__(64) void k_agg(const unsigned int* __restrict__ XW,
                                            const float* __restrict__ dis,
                                            const int* __restrict__ rowptr,
                                            const unsigned* __restrict__ epk,
                                            const float* __restrict__ bias,
                                            void* __restrict__ OUT, int N) {
    int n = blockIdx.x;
    if (n >= N) return;
    int lane = threadIdx.x;
    unsigned a = XW[(size_t)n * 64 + lane];
    float ax = bflo(a);
    float ay = bfhi(a);
    int e0 = rowptr[n], e1 = rowptr[n + 1];
    int e = e0;
    for (; e < e1 && (e & 3); ++e) {
        unsigned p = epk[e];
        unsigned v = GATHER(p);
        float nn = f16u(p >> 17);
        ax += nn * bflo(v);
        ay += nn * bfhi(v);
    }
    for (; e + 16 <= e1; e += 16) {
        uintx4 q0 = __builtin_nontemporal_load((const uintx4*)&epk[e]);
        uintx4 q1 = __builtin_nontemporal_load((const uintx4*)&epk[e + 4]);
        uintx4 q2 = __builtin_nontemporal_load((const uintx4*)&epk[e + 8]);
        uintx4 q3 = __builtin_nontemporal_load((const uintx4*)&epk[e + 12]);
        unsigned v0 = GATHER(q0[0]), v1 = GATHER(q0[1]), v2 = GATHER(q0[2]), v3 = GATHER(q0[3]);
        unsigned v4 = GATHER(q1[0]), v5 = GATHER(q1[1]), v6 = GATHER(q1[2]), v7 = GATHER(q1[3]);
        unsigned v8 = GATHER(q2[0]), v9 = GATHER(q2[1]), va = GATHER(q2[2]), vb = GATHER(q2[3]);
        unsigned vc = GATHER(q3[0]), vd = GATHER(q3[1]), ve = GATHER(q3[2]), vf = GATHER(q3[3]);
        ACC4(q0, v0, v1, v2, v3);
        ACC4(q1, v4, v5, v6, v7);
        ACC4(q2, v8, v9, va, vb);
        ACC4(q3, vc, vd, ve, vf);
    }
    for (; e + 4 <= e1; e += 4) {
        uintx4 q = __builtin_nontemporal_load((const uintx4*)&epk[e]);
        unsigned v0 = GATHER(q[0]), v1 = GATHER(q[1]), v2 = GATHER(q[2]), v3 = GATHER(q[3]);
        ACC4(q, v0, v1, v2, v3);
    }
    for (; e < e1; ++e) {
        unsigned p = epk[e];
        unsigned v = GATHER(p);
        float nn = f16u(p >> 17);
        ax += nn * bflo(v);
        ay += nn * bfhi(v);
    }
    float dn = dis[n];
    float2 b = ((const float2*)bias)[lane];
    ax = fmaxf(fmaf(dn, ax, b.x), 0.f);
    ay = fmaxf(fmaf(dn, ay, b.y), 0.f);
    if (OUT_BF16) {
        unsigned o = ((unsigned)f2bf(ay) << 16) | f2bf(ax);
        ((unsigned*)OUT)[(size_t)n * 64 + lane] = o;
    } else {
        ((float2*)OUT)[(size_t)n * 64 + lane] = make_float2(ax, ay);
    }
}

__device__ __forceinline__ int lowerb(const int* a, int n, int v) {
    int lo = 0, hi = n;
    while (lo < hi) {
        int m = (lo + hi) >> 1;
        if (a[m] < v) lo = m + 1; else hi = m;
    }
    return lo;
}

// Stage 1: 64 graphs x PCH chunks, partial channel sums.
__global__ __launch_bounds__(128) void k_pool1(const float* __restrict__ H,
                                               const int* __restrict__ batch,
                                               float* __restrict__ partial, int N) {
    __shared__ int ss[2];
    int g = blockIdx.x / PCH;
    int k = blockIdx.x % PCH;
    if (threadIdx.x == 0) {
        ss[0] = lowerb(batch, N, g);
        ss[1] = lowerb(batch, N, g + 1);
    }
    __syncthreads();
    int s = ss[0], len = ss[1] - ss[0];
    int cs = s + (int)(((long long)len * k) / PCH);
    int ce = s + (int)(((long long)len * (k + 1)) / PCH);
    int ch = threadIdx.x;
    float a0 = 0.f, a1 = 0.f;
    int n = cs;
    for (; n + 2 <= ce; n += 2) {
        a0 += H[(size_t)(n + 0) * CH + ch];
        a1 += H[(size_t)(n + 1) * CH + ch];
    }
    for (; n < ce; ++n) a0 += H[(size_t)n * CH + ch];
    partial[(size_t)blockIdx.x * CH + ch] = a0 + a1;
}

// Stage 2: reduce PCH partials per graph, divide by count.
__global__ __launch_bounds__(128) void k_pool2(const float* __restrict__ partial,
                                               const int* __restrict__ batch,
                                               float* __restrict__ P, int N) {
    __shared__ int ss[2];
    int g = blockIdx.x;
    if (threadIdx.x == 0) {
        ss[0] = lowerb(batch, N, g);
        ss[1] = lowerb(batch, N, g + 1);
    }
    __syncthreads();
    int ch = threadIdx.x;
    float a = 0.f;
#pragma unroll
    for (int k = 0; k < PCH; ++k) a += partial[(size_t)(g * PCH + k) * CH + ch];
    float c = (float)(ss[1] - ss[0]);
    P[(size_t)g * CH + ch] = a / fmaxf(c, 1.f);
}

extern "C" void kernel_launch(void* const* d_in, const int* in_sizes, int n_in,
                              void* d_out, int out_size, void* d_ws, size_t ws_size,
                              hipStream_t stream) {
    const float* x     = (const float*)d_in[0];
    const int*   ei    = (const int*)d_in[1];
    const float* ew    = (const float*)d_in[2];
    const int*   batch = (const int*)d_in[3];
    const float* W1    = (const float*)d_in[4];
    const float* b1    = (const float*)d_in[5];
    const float* W2    = (const float*)d_in[6];
    const float* b2    = (const float*)d_in[7];

    int N = in_sizes[0] / CH;   // 50000
    int E = in_sizes[1] / 2;    // 1600000
    const int* row = ei;
    const int* col = ei + E;

    float* out    = (float*)d_out;
    float* h      = out;
    float* pooled = out + (size_t)N * CH;

    int NB    = (N + 127) >> BSH;          // 391
    int chunk = (E + NBLK - 1) / NBLK;     // 1563
    int n2    = NB * NBLK;                 // 400384

    // ws: dis | rowptr | H(n2+1; partial aliases) | bsum+cnt | epk | bufA | bufB
    char* wsb = (char*)d_ws;
    size_t oN  = ((size_t)N * 4 + 255) & ~(size_t)255;
    size_t oN1 = ((size_t)(N + 1) * 4 + 255) & ~(size_t)255;
    size_t oH  = ((size_t)(n2 + 1) * 4 + 255) & ~(size_t)255;
    size_t oB  = 8192;
    size_t oE1 = ((size_t)E * 4 + 255) & ~(size_t)255;
    size_t oE2 = ((size_t)E * 8 + 255) & ~(size_t)255;  // 12.8MB (>= N*CH*2)
    float* dis    = (float*)wsb;
    int*   rowptr = (int*)(wsb + oN);
    int*   H      = (int*)(wsb + oN + oN1);
    int*   bsum   = (int*)(wsb + oN + oN1 + oH);
    int*   cnt    = bsum + 1024;
    unsigned* epk = (unsigned*)(wsb + oN + oN1 + oH + oB);
    char*  bufA   = wsb + oN + oN1 + oH + oB + oE1;
    char*  bufB   = bufA + oE2;
    int2*  pairs2 = (int2*)bufA;
    unsigned short* xw = (unsigned short*)bufA;
    unsigned short* h1 = (unsigned short*)bufB;
    float* partial = (float*)H;    // H dead after sort2; 1MB <= 1.6MB

    int sb2 = (n2 + 1023) / 1024;  // 391

    // ---- CSR build: two-level LDS counting sort (no global atomics) ----
    k_sort1a<<<NBLK, 256, 0, stream>>>(col, H, cnt, E, NB, chunk);
    k_scan1<<<sb2, 1024, 0, stream>>>(H, bsum, cnt, n2, sb2);
    k_sort1b<<<NBLK, 256, 0, stream>>>(row, col, ew, H, bsum, pairs2, E, NB, chunk);
    k_sort2<<<NB, 256, 0, stream>>>(H, bsum, pairs2, epk, rowptr, dis, E, N, NB);

    int gb = (N + 127) / 128;
    // ---- layer 1 ----
    k_gemm_f32<<<gb, 512, 0, stream>>>(x, W1, dis, xw, N);
    k_agg<true><<<N, 64, 0, stream>>>((const unsigned int*)xw, dis, rowptr, epk, b1, h1, N);
    // ---- layer 2 ----
    k_gemm_bf16<<<gb, 512, 0, stream>>>(h1, W2, dis, xw, N);
    k_agg<false><<<N, 64, 0, stream>>>((const unsigned int*)xw, dis, rowptr, epk, b2, h, N);
    // ---- mean pool (two-stage) ----
    k_pool1<<<64 * PCH, 128, 0, stream>>>(h, batch, partial, N);
    k_pool2<<<64, 128, 0, stream>>>(partial, batch, pooled, N);
}